// Round 1
// baseline (1161.136 us; speedup 1.0000x reference)
//
#include <hip/hip_runtime.h>

// EdgeClassifierGNN: 3x SAGEConv(mean) + edge MLP on MI355X.
// Strategy: build CSR by dst once per call (int atomics only), then
// gather-based mean aggregation (wave-per-node, lane=feature, coalesced
// 256B row reads). Edge MLP restructured: A[i]=h3[i]@Wm1[:64]+bm1,
// B[i]=h3[i]@Wm1[64:128] precomputed per node; per-edge work is then
// A[src]+B[dst]+attr@Wm1[128:] -> relu -> @Wm2 -> relu -> @Wm3.

#define WAVE 64

__global__ __launch_bounds__(256) void hist_kernel(const int* __restrict__ ei, int E,
                                                   int* __restrict__ cnt) {
    int e = blockIdx.x * blockDim.x + threadIdx.x;
    if (e < E) atomicAdd(&cnt[ei[E + e]], 1);
}

__global__ __launch_bounds__(1024) void scan_kernel(const int* __restrict__ cnt,
                                                    int* __restrict__ rowptr, int N) {
    __shared__ int sums[1024];
    int t = threadIdx.x;
    int chunk = (N + 1023) >> 10;
    int start = t * chunk;
    int end = min(start + chunk, N);
    int s = 0;
    for (int i = start; i < end; ++i) s += cnt[i];
    sums[t] = s;
    __syncthreads();
    // Hillis-Steele inclusive scan over 1024 thread sums
    for (int off = 1; off < 1024; off <<= 1) {
        int v = (t >= off) ? sums[t - off] : 0;
        __syncthreads();
        sums[t] += v;
        __syncthreads();
    }
    int run = (t == 0) ? 0 : sums[t - 1];
    if (t == 0) rowptr[0] = 0;
    for (int i = start; i < end; ++i) { run += cnt[i]; rowptr[i + 1] = run; }
}

__global__ __launch_bounds__(256) void fill_kernel(const int* __restrict__ ei, int E,
                                                   const int* __restrict__ rowptr,
                                                   int* __restrict__ cursor,
                                                   int* __restrict__ col) {
    int e = blockIdx.x * blockDim.x + threadIdx.x;
    if (e >= E) return;
    int s = ei[e], d = ei[E + e];
    int p = rowptr[d] + atomicAdd(&cursor[d], 1);
    col[p] = s;
}

// SAGE layer 1: 16 -> 64. One wave per node.
__global__ __launch_bounds__(256) void sage16_kernel(
        const float* __restrict__ x, const int* __restrict__ rowptr,
        const int* __restrict__ col, const float* __restrict__ Wl,
        const float* __restrict__ Wr, const float* __restrict__ b,
        float* __restrict__ out, int N) {
    int lane = threadIdx.x & 63;
    int wid  = (blockIdx.x * blockDim.x + threadIdx.x) >> 6;
    int nwv  = (gridDim.x * blockDim.x) >> 6;
    int f = lane & 15, g = lane >> 4;
    for (int i = wid; i < N; i += nwv) {
        int s0 = rowptr[i], s1 = rowptr[i + 1];
        float acc = 0.f;
        for (int j = s0 + g; j < s1; j += 4)
            acc += x[(size_t)col[j] * 16 + f];
        acc += __shfl_xor(acc, 16);
        acc += __shfl_xor(acc, 32);
        float inv  = 1.0f / fmaxf((float)(s1 - s0), 1.0f);
        float mean = acc * inv;              // lane l holds mean[l&15]
        float xi   = x[(size_t)i * 16 + f];  // lane l holds x[i][l&15]
        float o = b[lane];
        #pragma unroll
        for (int ff = 0; ff < 16; ++ff) {
            float m  = __shfl(mean, ff);
            float xv = __shfl(xi, ff);
            o += m * Wl[ff * 64 + lane];
            o += xv * Wr[ff * 64 + lane];
        }
        out[(size_t)i * 64 + lane] = fmaxf(o, 0.f);
    }
}

// SAGE layer 64 -> 64. One wave per node, lane = channel.
__global__ __launch_bounds__(256) void sage64_kernel(
        const float* __restrict__ hin, const int* __restrict__ rowptr,
        const int* __restrict__ col, const float* __restrict__ Wl,
        const float* __restrict__ Wr, const float* __restrict__ b,
        float* __restrict__ out, int N) {
    int lane = threadIdx.x & 63;
    int wid  = (blockIdx.x * blockDim.x + threadIdx.x) >> 6;
    int nwv  = (gridDim.x * blockDim.x) >> 6;
    for (int i = wid; i < N; i += nwv) {
        int s0 = rowptr[i], s1 = rowptr[i + 1];
        float acc0 = 0.f, acc1 = 0.f;
        int j = s0;
        for (; j + 1 < s1; j += 2) {
            int c0 = col[j], c1 = col[j + 1];
            acc0 += hin[(size_t)c0 * 64 + lane];
            acc1 += hin[(size_t)c1 * 64 + lane];
        }
        if (j < s1) acc0 += hin[(size_t)col[j] * 64 + lane];
        float inv  = 1.0f / fmaxf((float)(s1 - s0), 1.0f);
        float mean = (acc0 + acc1) * inv;
        float hi   = hin[(size_t)i * 64 + lane];
        float o = b[lane];
        #pragma unroll
        for (int ff = 0; ff < 64; ++ff) {
            float m  = __shfl(mean, ff);
            float hv = __shfl(hi, ff);
            o += m * Wl[ff * 64 + lane];
            o += hv * Wr[ff * 64 + lane];
        }
        out[(size_t)i * 64 + lane] = fmaxf(o, 0.f);
    }
}

// Per-node precompute: A[i] = h3[i] @ Wm1[0:64] + bm1 ; B[i] = h3[i] @ Wm1[64:128]
__global__ __launch_bounds__(256) void precomp_kernel(
        const float* __restrict__ h3, const float* __restrict__ Wm1,
        const float* __restrict__ bm1, float* __restrict__ A,
        float* __restrict__ Bf, int N) {
    int lane = threadIdx.x & 63;
    int wid  = (blockIdx.x * blockDim.x + threadIdx.x) >> 6;
    int nwv  = (gridDim.x * blockDim.x) >> 6;
    for (int i = wid; i < N; i += nwv) {
        float hi = h3[(size_t)i * 64 + lane];
        float a  = bm1[lane];
        float bb = 0.f;
        #pragma unroll
        for (int ff = 0; ff < 64; ++ff) {
            float hv = __shfl(hi, ff);
            a  += hv * Wm1[ff * 64 + lane];
            bb += hv * Wm1[(64 + ff) * 64 + lane];
        }
        A[(size_t)i * 64 + lane]  = a;
        Bf[(size_t)i * 64 + lane] = bb;
    }
}

// Edge MLP: wave per edge.
__global__ __launch_bounds__(256) void edge_kernel(
        const float* __restrict__ A, const float* __restrict__ Bf,
        const int* __restrict__ ei, const float* __restrict__ attr,
        const float* __restrict__ Wm1, const float* __restrict__ Wm2,
        const float* __restrict__ Wm3, const float* __restrict__ bm2,
        const float* __restrict__ bm3, float* __restrict__ out, int E) {
    int lane = threadIdx.x & 63;
    int wid  = (blockIdx.x * blockDim.x + threadIdx.x) >> 6;
    int nwv  = (gridDim.x * blockDim.x) >> 6;
    int p = lane & 31, half = lane >> 5;
    float w3    = Wm3[p];
    float bias2 = bm2[p];
    float bias3 = bm3[0];
    for (int e = wid; e < E; e += nwv) {
        int s = ei[e], d = ei[E + e];
        float z1 = A[(size_t)s * 64 + lane] + Bf[(size_t)d * 64 + lane];
        #pragma unroll
        for (int k = 0; k < 8; ++k)
            z1 += attr[(size_t)e * 8 + k] * Wm1[(128 + k) * 64 + lane];
        z1 = fmaxf(z1, 0.f);
        // z2[p] = relu(sum_o z1[o]*Wm2[o][p] + bm2[p]); split o-sum across halves
        float z2 = 0.f;
        #pragma unroll
        for (int k = 0; k < 32; ++k) {
            int o = half * 32 + k;
            z2 += __shfl(z1, o) * Wm2[o * 32 + p];
        }
        z2 += __shfl_xor(z2, 32);
        z2 = fmaxf(z2 + bias2, 0.f);
        float t = (lane < 32) ? z2 * w3 : 0.f;
        t += __shfl_xor(t, 16);
        t += __shfl_xor(t, 8);
        t += __shfl_xor(t, 4);
        t += __shfl_xor(t, 2);
        t += __shfl_xor(t, 1);
        if (lane == 0) out[e] = t + bias3;
    }
}

extern "C" void kernel_launch(void* const* d_in, const int* in_sizes, int n_in,
                              void* d_out, int out_size, void* d_ws, size_t ws_size,
                              hipStream_t stream) {
    const float* x    = (const float*)d_in[0];
    const int*   ei   = (const int*)d_in[1];
    const float* attr = (const float*)d_in[2];
    const float* W1l  = (const float*)d_in[3];
    const float* W1r  = (const float*)d_in[4];
    const float* b1   = (const float*)d_in[5];
    const float* W2l  = (const float*)d_in[6];
    const float* W2r  = (const float*)d_in[7];
    const float* b2   = (const float*)d_in[8];
    const float* W3l  = (const float*)d_in[9];
    const float* W3r  = (const float*)d_in[10];
    const float* b3   = (const float*)d_in[11];
    const float* Wm1  = (const float*)d_in[12];
    const float* bm1  = (const float*)d_in[13];
    const float* Wm2  = (const float*)d_in[14];
    const float* bm2  = (const float*)d_in[15];
    const float* Wm3  = (const float*)d_in[16];
    const float* bm3  = (const float*)d_in[17];
    float* out = (float*)d_out;

    const int N = in_sizes[0] / 16;
    const int E = in_sizes[1] / 2;

    // Workspace layout
    char* ws = (char*)d_ws;
    size_t off = 0;
    int* cnt    = (int*)(ws + off); off += (size_t)N * 4;
    int* cursor = (int*)(ws + off); off += (size_t)N * 4;
    int* rowptr = (int*)(ws + off); off += (size_t)(N + 1) * 4;
    off = (off + 255) & ~(size_t)255;
    int* col    = (int*)(ws + off); off += (size_t)E * 4;
    off = (off + 255) & ~(size_t)255;
    float* buf0 = (float*)(ws + off); off += (size_t)N * 64 * 4;  // h1, later A
    float* buf1 = (float*)(ws + off); off += (size_t)N * 64 * 4;  // h2, later B
    float* buf2 = (float*)(ws + off); off += (size_t)N * 64 * 4;  // h3

    // zero cnt + cursor (adjacent)
    hipMemsetAsync(ws, 0, (size_t)N * 8, stream);

    const int TB = 256;
    int ebBlocks = (E + TB - 1) / TB;
    int nwBlocks = (N * 64 + TB - 1) / TB;   // one wave per node

    hist_kernel<<<ebBlocks, TB, 0, stream>>>(ei, E, cnt);
    scan_kernel<<<1, 1024, 0, stream>>>(cnt, rowptr, N);
    fill_kernel<<<ebBlocks, TB, 0, stream>>>(ei, E, rowptr, cursor, col);

    sage16_kernel<<<nwBlocks, TB, 0, stream>>>(x, rowptr, col, W1l, W1r, b1, buf0, N);
    sage64_kernel<<<nwBlocks, TB, 0, stream>>>(buf0, rowptr, col, W2l, W2r, b2, buf1, N);
    sage64_kernel<<<nwBlocks, TB, 0, stream>>>(buf1, rowptr, col, W3l, W3r, b3, buf2, N);

    precomp_kernel<<<nwBlocks, TB, 0, stream>>>(buf2, Wm1, bm1, buf0, buf1, N);

    int egBlocks = 8192;  // grid-stride, ~24 edges per wave
    edge_kernel<<<egBlocks, TB, 0, stream>>>(buf0, buf1, ei, attr, Wm1, Wm2, Wm3,
                                             bm2, bm3, out, E);
}